// Round 6
// baseline (60.180 us; speedup 1.0000x reference)
//
#include <hip/hip_runtime.h>

#define QDIM 21
#define NDIM 1368
#define OUTSTRIDE 64000

typedef __attribute__((ext_vector_type(4))) float f32x4;
typedef __attribute__((ext_vector_type(8))) short bf16x8s;
typedef __attribute__((ext_vector_type(4))) unsigned int u32x4;

typedef __attribute__((address_space(1))) const unsigned int* gas_p;
typedef __attribute__((address_space(3))) unsigned int* las_p;

static __device__ __forceinline__ void gload16(const float* g, char* l) {
    __builtin_amdgcn_global_load_lds((gas_p)(const void*)g, (las_p)(void*)l, 16, 0, 0);
}

// pack two f32 -> bf16x2 (round-half-up)
static __device__ __forceinline__ unsigned int pk2(float lo, float hi) {
    unsigned int a = __float_as_uint(lo) + 0x8000u;
    unsigned int b = __float_as_uint(hi) + 0x8000u;
    return __builtin_amdgcn_perm(b, a, 0x07060302);  // {a>>16, b>>16} -> elem0=lo
}

static __device__ __forceinline__ bf16x8s pack8(float4 lo, float4 hi) {
    u32x4 p;
    p[0] = pk2(lo.x, lo.y);
    p[1] = pk2(lo.z, lo.w);
    p[2] = pk2(hi.x, hi.y);
    p[3] = pk2(hi.z, hi.w);
    return __builtin_bit_cast(bf16x8s, p);
}

// One 2-wave block computes C[0:64, n0:n0+32] for window position p.
//  - A (x windows): loaded DIRECTLY global->reg each k-step (8 contiguous f32
//    per fragment; x is L2-resident). No LDS, no inter-wave sharing needed.
//  - B (weights): gload_lds ring, 3 stages x B[32][32]f32 = 12 KB total.
//    Stage row = 128 B = 8 segs; XOR swizzle seg^(row&7) via pre-swizzled
//    global source; read side applies the same XOR.
//  - Per tile: wait vmcnt(2) [B(t) landed]; s_barrier(2 waves); A-loads(t);
//    issue STAGE(t+2) into stage (t-1)%3 (its reads certified by this
//    barrier); vmcnt(2) [A done, B(t+1) done, B(t+2) in flight]; ds_read B;
//    pack; 4 MFMA.
template<int WLOG2, int NTX, int D, int P, int S, int K>
__device__ __forceinline__ void fbk_body(const float* __restrict__ x,
                                         const float* __restrict__ W,
                                         float* __restrict__ out, int bid,
                                         char* lds) {
    constexpr int WWIN = 1 << WLOG2;
    constexpr int G = (K + 31) / 32;          // 42 / 21 / 11
    constexpr bool TAIL = (K % 32) != 0;      // fb0 only (K=336)
    constexpr int KREM = K % 32;              // 16 for fb0

    const int n0 = (bid % NTX) * 32;
    const int p  = bid / NTX;
    const int start = (p == P - 1) ? (NDIM - WWIN) : p * S;

    const int tid  = threadIdx.x;
    const int wid  = tid >> 6;                // 0..1
    const int lane = tid & 63;
    const int wm = wid * 32;                  // wave's M offset (batch rows)
    const int lr = lane & 15;
    const int hi = lane >> 4;
    const int kb = hi * 8;

    // ---- B staging constants (per wave: rows wid*16 .. wid*16+15, 2 insts)
    const int lrow = lane >> 3;                   // 0..7 (row within inst)
    const int g4   = ((lane & 7) ^ lrow) * 4;     // pre-swizzled source col
    const float* Wp  = W + (size_t)(p * D + n0) * K;
    const float* wb0 = Wp + (size_t)(wid * 16 + lrow) * K;
    const float* wb1 = wb0 + (size_t)8 * K;
    char* ldsw = lds + wid * 2048;                // wave's rows base in stage

    // ---- A direct-load pointers (advance per k-step)
    const int q0 = kb >> WLOG2;
    const int j0 = kb & (WWIN - 1);
    const float* pA0 = x + ((size_t)(wm + lr) * QDIM + q0) * NDIM + start + j0;
    const float* pA1 = pA0 + (size_t)16 * QDIM * NDIM;

    // ---- B fragment read offsets (swizzled); row&7 == lr&7 for both rows
    const int x7 = lr & 7;
    const int c0 = ((hi * 2)     ^ x7) * 16;
    const int c1 = ((hi * 2 + 1) ^ x7) * 16;
    const int oB0 = lr * 128;
    const int oB1 = (16 + lr) * 128;

    f32x4 acc[2][2] = {};   // [mi][ni]

    auto STAGE = [&](int t, int sb) {
        int f = t * 32 + g4;
        if constexpr (TAIL) f = (f > K - 4) ? (K - 4) : f;  // garbage; A zeroed
        char* d = ldsw + sb;
        gload16(wb0 + f, d);
        gload16(wb1 + f, d + 1024);
    };

    STAGE(0, 0);
    STAGE(1, 4096);

    int cs = 0;   // byte base of current tile's stage (0/4096/8192)
    #pragma unroll 1
    for (int t = 0; t < G; ++t) {
        asm volatile("s_waitcnt vmcnt(2)" ::: "memory");   // B(t) landed
        __builtin_amdgcn_sched_barrier(0);
        __builtin_amdgcn_s_barrier();
        __builtin_amdgcn_sched_barrier(0);

        // A loads for this tile (L2-resident x), straight to registers
        const float* qa0 = pA0;
        const float* qa1 = pA1;
        if constexpr (TAIL) {
            if (t == G - 1 && kb >= KREM) { qa0 = x; qa1 = x; }  // safe dummy
        }
        float4 a00 = *(const float4*)qa0;
        float4 a01 = *(const float4*)(qa0 + 4);
        float4 a10 = *(const float4*)qa1;
        float4 a11 = *(const float4*)(qa1 + 4);

        // stage B(t+2) into stage (t-1)%3 (reads certified by this barrier)
        if (t + 2 < G) {
            int pb = (cs == 0) ? 8192 : cs - 4096;
            STAGE(t + 2, pb);
            asm volatile("s_waitcnt vmcnt(2)" ::: "memory"); // A + B(t+1) done
        } else {
            asm volatile("s_waitcnt vmcnt(0)" ::: "memory");
        }
        __builtin_amdgcn_sched_barrier(0);

        const char* sb = lds + cs;
        float4 b00 = *(const float4*)(sb + oB0 + c0);
        float4 b01 = *(const float4*)(sb + oB0 + c1);
        float4 b10 = *(const float4*)(sb + oB1 + c0);
        float4 b11 = *(const float4*)(sb + oB1 + c1);

        if constexpr (TAIL) {
            if (t == G - 1 && kb >= KREM) {
                float4 z = make_float4(0.f, 0.f, 0.f, 0.f);
                a00 = z; a01 = z; a10 = z; a11 = z;   // zero-A kills garbage B
            }
        }

        bf16x8s A0 = pack8(a00, a01);
        bf16x8s A1 = pack8(a10, a11);
        bf16x8s B0 = pack8(b00, b01);
        bf16x8s B1 = pack8(b10, b11);

        acc[0][0] = __builtin_amdgcn_mfma_f32_16x16x32_bf16(A0, B0, acc[0][0], 0, 0, 0);
        acc[0][1] = __builtin_amdgcn_mfma_f32_16x16x32_bf16(A0, B1, acc[0][1], 0, 0, 0);
        acc[1][0] = __builtin_amdgcn_mfma_f32_16x16x32_bf16(A1, B0, acc[1][0], 0, 0, 0);
        acc[1][1] = __builtin_amdgcn_mfma_f32_16x16x32_bf16(A1, B1, acc[1][1], 0, 0, 0);

        // advance A pointers to next k-step
        if constexpr (WLOG2 == 6) {
            int adv = (t & 1) ? (NDIM - 32) : 32;   // j alternates within q
            pA0 += adv; pA1 += adv;
        } else {
            pA0 += (32 >> WLOG2) * NDIM;
            pA1 += (32 >> WLOG2) * NDIM;
        }
        cs = (cs == 8192) ? 0 : cs + 4096;
    }

    // epilogue: C/D layout col = lane&15, row = (lane>>4)*4 + r
    const int colbase = p * D + n0;
    #pragma unroll
    for (int mi = 0; mi < 2; ++mi) {
        #pragma unroll
        for (int ni = 0; ni < 2; ++ni) {
            int col = colbase + ni * 16 + lr;
            int rbase = wm + mi * 16 + hi * 4;
            #pragma unroll
            for (int r = 0; r < 4; ++r) {
                out[(size_t)(rbase + r) * OUTSTRIDE + col] = acc[mi][ni][r];
            }
        }
    }
}

// Fused dispatch: 2000 blocks x 128 threads, longest (fb2) first.
__global__ __launch_bounds__(128, 4)
void fbk_fused(const float* __restrict__ x,  const float* __restrict__ w0,
               const float* __restrict__ w1, const float* __restrict__ w2,
               float* __restrict__ out) {
    __shared__ __align__(16) char lds[12288];   // 3 stages x 4 KB
    const int bid = blockIdx.x;
    if (bid < 656) {
        // fb2: w=64, s=16, d=256, P=82, K=1344, 8 n-tiles of 32
        fbk_body<6, 8, 256, 82, 16, 1344>(x, w2, out + 43008, bid, lds);
    } else if (bid < 1324) {
        // fb1: w=32, s=8, d=128, P=167, K=672, 4 n-tiles of 32
        fbk_body<5, 4, 128, 167, 8, 672>(x, w1, out + 21632, bid - 656, lds);
    } else {
        // fb0: w=16, s=4, d=64, P=338, K=336, 2 n-tiles of 32
        fbk_body<4, 2, 64, 338, 4, 336>(x, w0, out, bid - 1324, lds);
    }
}

extern "C" void kernel_launch(void* const* d_in, const int* in_sizes, int n_in,
                              void* d_out, int out_size, void* d_ws, size_t ws_size,
                              hipStream_t stream) {
    const float* x  = (const float*)d_in[0];
    const float* w0 = (const float*)d_in[1];
    const float* w1 = (const float*)d_in[2];
    const float* w2 = (const float*)d_in[3];
    float* out = (float*)d_out;
    fbk_fused<<<dim3(2000), 128, 0, stream>>>(x, w0, w1, w2, out);
}

// Round 7
// 59.165 us; speedup vs baseline: 1.0171x; 1.0171x over previous
//
#include <hip/hip_runtime.h>

#define QDIM 21
#define NDIM 1368
#define OUTSTRIDE 64000

typedef __attribute__((ext_vector_type(4))) float f32x4;
typedef __attribute__((ext_vector_type(8))) short bf16x8s;
typedef __attribute__((ext_vector_type(4))) unsigned int u32x4;

typedef __attribute__((address_space(1))) const unsigned int* gas_p;
typedef __attribute__((address_space(3))) unsigned int* las_p;

static __device__ __forceinline__ void gload16(const float* g, char* l) {
    __builtin_amdgcn_global_load_lds((gas_p)(const void*)g, (las_p)(void*)l, 16, 0, 0);
}

// pack two f32 -> bf16x2 (round-half-up)
static __device__ __forceinline__ unsigned int pk2(float lo, float hi) {
    unsigned int a = __float_as_uint(lo) + 0x8000u;
    unsigned int b = __float_as_uint(hi) + 0x8000u;
    return __builtin_amdgcn_perm(b, a, 0x07060302);
}

static __device__ __forceinline__ bf16x8s pack8(float4 lo, float4 hi) {
    u32x4 p;
    p[0] = pk2(lo.x, lo.y);
    p[1] = pk2(lo.z, lo.w);
    p[2] = pk2(hi.x, hi.y);
    p[3] = pk2(hi.z, hi.w);
    return __builtin_bit_cast(bf16x8s, p);
}

// One 4-wave block computes C[0:64, n0:n0+64] for window position p.
// gload_lds ring pipeline: 3 stages x (A[64][32]f32 + B[64][32]f32) = 48 KB.
// Stage LDS row = 128 B = 8 segs of 16 B; XOR swizzle: LDS[r][s] holds global
// seg s^(r&7)  (loader fetches g=(l&7)^(l>>3); reader reads s=g^(r&7)).
// Per tile: waitcnt vmcnt(4); s_barrier; ds_read frags; pack; 4 MFMA;
// issue STAGE(t+2) into stage (t-1)%3 (reads of t-1 certified by this barrier).
template<int WLOG2, int NTX, int D, int P, int S, int K>
__device__ __forceinline__ void fbk_body(const float* __restrict__ x,
                                         const float* __restrict__ W,
                                         float* __restrict__ out, int bid,
                                         char* ldsraw) {
    constexpr int WWIN = 1 << WLOG2;
    constexpr int G = (K + 31) / 32;          // 42 / 21 / 11
    constexpr bool TAIL = (K % 32) != 0;      // fb0 only (K=336)
    constexpr int FMAXC = (K - 4) & ~3;       // aligned clamp for tail loads

    const int n0 = (bid % NTX) * 64;
    const int p  = bid / NTX;
    const int start = (p == P - 1) ? (NDIM - WWIN) : p * S;

    const int tid  = threadIdx.x;
    const int wid  = tid >> 6;
    const int lane = tid & 63;
    const int wm = (wid >> 1) * 32;
    const int wn = (wid & 1) * 32;
    const int lr = lane & 15;
    const int hi = lane >> 4;
    const int kb = hi * 8;

    // ---- staging lane constants (per-wave: 2 A-insts + 2 B-insts, 8 rows each)
    const int lrow = lane >> 3;                   // row within instruction
    const int g4   = ((lane & 7) ^ lrow) * 4;     // inverse-swizzled source col (floats)
    const int r0   = 16 * wid + lrow;             // global row of inst 0
    const float* xb0 = x + (size_t)r0 * QDIM * NDIM + start;
    const float* Wp  = W + (size_t)(p * D + n0) * K;
    const float* wb0 = Wp + (size_t)r0 * K;
    const float* wb1 = wb0 + (size_t)8 * K;
    const int wA = 2048 * wid;                    // wave's A byte offset in stage

    auto STAGE = [&](int t, int sbase) {
        int f = t * 32 + g4;
        if constexpr (TAIL) f = (f > FMAXC) ? FMAXC : f;   // garbage, zeroed at read
        int q = f >> WLOG2;
        int j = f & (WWIN - 1);
        const float* ga = xb0 + q * NDIM + j;
        char* la = ldsraw + sbase + wA;
        char* lb = ldsraw + sbase + 8192 + wA;
        gload16(ga, la);
        gload16(ga + (size_t)8 * QDIM * NDIM, la + 1024);
        gload16(wb0 + f, lb);
        gload16(wb1 + f, lb + 1024);
    };

    // ---- fragment-read constants (swizzled): (wm|wn)+16 keeps r&7 == lr&7
    const int x7 = lr & 7;
    const int c0 = ((hi * 2)     ^ x7) * 16;
    const int c1 = ((hi * 2 + 1) ^ x7) * 16;
    const int oA0 = (wm + lr) * 128;
    const int oA1 = (wm + 16 + lr) * 128;
    const int oB0 = 8192 + (wn + lr) * 128;
    const int oB1 = 8192 + (wn + 16 + lr) * 128;

    f32x4 acc[2][2] = {};

    STAGE(0, 0);
    STAGE(1, 16384);

    int cs = 0;   // byte base of current tile's stage
    #pragma unroll 1
    for (int t = 0; t < G; ++t) {
        if (t + 1 < G) { asm volatile("s_waitcnt vmcnt(4)" ::: "memory"); }
        else           { asm volatile("s_waitcnt vmcnt(0)" ::: "memory"); }
        __builtin_amdgcn_sched_barrier(0);
        __builtin_amdgcn_s_barrier();
        __builtin_amdgcn_sched_barrier(0);

        const char* sb = ldsraw + cs;
        float4 a00 = *(const float4*)(sb + oA0 + c0);
        float4 a01 = *(const float4*)(sb + oA0 + c1);
        float4 a10 = *(const float4*)(sb + oA1 + c0);
        float4 a11 = *(const float4*)(sb + oA1 + c1);
        float4 b00 = *(const float4*)(sb + oB0 + c0);
        float4 b01 = *(const float4*)(sb + oB0 + c1);
        float4 b10 = *(const float4*)(sb + oB1 + c0);
        float4 b11 = *(const float4*)(sb + oB1 + c1);

        if constexpr (TAIL) {
            if (t == G - 1 && kb >= (K & 31)) {     // fully-invalid fragments
                float4 z = make_float4(0.f, 0.f, 0.f, 0.f);
                a00 = z; a01 = z; a10 = z; a11 = z;
            }
        }

        bf16x8s A0 = pack8(a00, a01);
        bf16x8s A1 = pack8(a10, a11);
        bf16x8s B0 = pack8(b00, b01);
        bf16x8s B1 = pack8(b10, b11);

        acc[0][0] = __builtin_amdgcn_mfma_f32_16x16x32_bf16(A0, B0, acc[0][0], 0, 0, 0);
        acc[0][1] = __builtin_amdgcn_mfma_f32_16x16x32_bf16(A0, B1, acc[0][1], 0, 0, 0);
        acc[1][0] = __builtin_amdgcn_mfma_f32_16x16x32_bf16(A1, B0, acc[1][0], 0, 0, 0);
        acc[1][1] = __builtin_amdgcn_mfma_f32_16x16x32_bf16(A1, B1, acc[1][1], 0, 0, 0);

        __builtin_amdgcn_sched_barrier(0);
        if (t + 2 < G) {
            int pb = (cs == 0) ? 32768 : cs - 16384;   // stage (t+2)%3 == (t-1)%3
            STAGE(t + 2, pb);
        }
        cs = (cs == 32768) ? 0 : cs + 16384;
    }

    // epilogue: C/D layout col = lane&15, row = (lane>>4)*4 + r
    const int colbase = p * D + n0;
    #pragma unroll
    for (int mi = 0; mi < 2; ++mi) {
        #pragma unroll
        for (int ni = 0; ni < 2; ++ni) {
            int col = colbase + wn + ni * 16 + lr;
            int rbase = wm + mi * 16 + hi * 4;
            #pragma unroll
            for (int r = 0; r < 4; ++r) {
                out[(size_t)(rbase + r) * OUTSTRIDE + col] = acc[mi][ni][r];
            }
        }
    }
}

// Fused dispatch: 1000 blocks, longest (fb2, 42 tiles) first for tail packing.
// XCD chunk swizzle (T1, bijective since 1000 = 8*125): physical blocks
// round-robin over 8 XCDs; remap so each XCD owns a CONTIGUOUS 125-block span
// (= contiguous p-range) -> the live x-slice per XCD (~1 MB) becomes
// L2-resident instead of every n-tile block re-pulling x across the fabric.
__global__ __launch_bounds__(256, 3)
void fbk_fused(const float* __restrict__ x,  const float* __restrict__ w0,
               const float* __restrict__ w1, const float* __restrict__ w2,
               float* __restrict__ out) {
    __shared__ __align__(16) char ldsraw[49152];   // 3 stages x 16 KB -> 3 blocks/CU
    const int bid = (blockIdx.x & 7) * 125 + (blockIdx.x >> 3);
    if (bid < 328) {
        // fb2: w=64, s=16, d=256, P=82, K=1344, 4 n-tiles
        fbk_body<6, 4, 256, 82, 16, 1344>(x, w2, out + 43008, bid, ldsraw);
    } else if (bid < 662) {
        // fb1: w=32, s=8, d=128, P=167, K=672, 2 n-tiles
        fbk_body<5, 2, 128, 167, 8, 672>(x, w1, out + 21632, bid - 328, ldsraw);
    } else {
        // fb0: w=16, s=4, d=64, P=338, K=336, 1 n-tile
        fbk_body<4, 1, 64, 338, 4, 336>(x, w0, out, bid - 662, ldsraw);
    }
}

extern "C" void kernel_launch(void* const* d_in, const int* in_sizes, int n_in,
                              void* d_out, int out_size, void* d_ws, size_t ws_size,
                              hipStream_t stream) {
    const float* x  = (const float*)d_in[0];
    const float* w0 = (const float*)d_in[1];
    const float* w1 = (const float*)d_in[2];
    const float* w2 = (const float*)d_in[3];
    float* out = (float*)d_out;
    fbk_fused<<<dim3(1000), 256, 0, stream>>>(x, w0, w1, w2, out);
}

// Round 8
// 41.686 us; speedup vs baseline: 1.4436x; 1.4193x over previous
//
#include <hip/hip_runtime.h>

#define QDIM 21
#define NDIM 1368
#define OUTSTRIDE 64000

typedef __attribute__((ext_vector_type(4))) float f32x4;
typedef __attribute__((ext_vector_type(8))) short bf16x8s;
typedef __attribute__((ext_vector_type(4))) unsigned int u32x4;

typedef __attribute__((address_space(1))) const unsigned int* gas_p;
typedef __attribute__((address_space(3))) unsigned int* las_p;

static __device__ __forceinline__ void gload16(const float* g, char* l) {
    __builtin_amdgcn_global_load_lds((gas_p)(const void*)g, (las_p)(void*)l, 16, 0, 0);
}

// pack two f32 -> bf16x2 (round-half-up)
static __device__ __forceinline__ unsigned int pk2(float lo, float hi) {
    unsigned int a = __float_as_uint(lo) + 0x8000u;
    unsigned int b = __float_as_uint(hi) + 0x8000u;
    return __builtin_amdgcn_perm(b, a, 0x07060302);
}

static __device__ __forceinline__ bf16x8s pack8(float4 lo, float4 hi) {
    u32x4 p;
    p[0] = pk2(lo.x, lo.y);
    p[1] = pk2(lo.z, lo.w);
    p[2] = pk2(hi.x, hi.y);
    p[3] = pk2(hi.z, hi.w);
    return __builtin_bit_cast(bf16x8s, p);
}

// Per-segment bijective chunk swizzle (m204): physical round-robin position
// within a segment of n blocks -> logical index such that each XCD owns a
// CONTIGUOUS chunk of ~n/8 logical blocks. Balance: every XCD gets 1/8 of
// EACH segment. Locality: contiguous p-range per XCD -> x-slice L2-resident.
static __device__ __forceinline__ int chunk_swz(int idx, int n) {
    int xcd = idx & 7;
    int i   = idx >> 3;
    int q = n >> 3, r = n & 7;
    int base = (xcd < r) ? xcd * (q + 1) : r * (q + 1) + (xcd - r) * q;
    return base + i;
}

// One 4-wave block computes C[0:64, n0:n0+64] for window position p.
// gload_lds ring pipeline: 3 stages x (A[64][32]f32 + B[64][32]f32) = 48 KB.
// Stage LDS row = 128 B = 8 segs of 16 B; XOR swizzle: LDS[r][s] holds global
// seg s^(r&7)  (loader fetches g=(l&7)^(l>>3); reader reads s=g^(r&7)).
// Per tile: waitcnt vmcnt(4); s_barrier; ds_read frags; pack; 4 MFMA;
// issue STAGE(t+2) into stage (t-1)%3 (reads of t-1 certified by this barrier).
template<int WLOG2, int NTX, int D, int P, int S, int K>
__device__ __forceinline__ void fbk_body(const float* __restrict__ x,
                                         const float* __restrict__ W,
                                         float* __restrict__ out, int bid,
                                         char* ldsraw) {
    constexpr int WWIN = 1 << WLOG2;
    constexpr int G = (K + 31) / 32;          // 42 / 21 / 11
    constexpr bool TAIL = (K % 32) != 0;      // fb0 only (K=336)
    constexpr int FMAXC = (K - 4) & ~3;       // aligned clamp for tail loads

    const int n0 = (bid % NTX) * 64;
    const int p  = bid / NTX;
    const int start = (p == P - 1) ? (NDIM - WWIN) : p * S;

    const int tid  = threadIdx.x;
    const int wid  = tid >> 6;
    const int lane = tid & 63;
    const int wm = (wid >> 1) * 32;
    const int wn = (wid & 1) * 32;
    const int lr = lane & 15;
    const int hi = lane >> 4;
    const int kb = hi * 8;

    // ---- staging lane constants (per-wave: 2 A-insts + 2 B-insts, 8 rows each)
    const int lrow = lane >> 3;                   // row within instruction
    const int g4   = ((lane & 7) ^ lrow) * 4;     // inverse-swizzled source col (floats)
    const int r0   = 16 * wid + lrow;             // global row of inst 0
    const float* xb0 = x + (size_t)r0 * QDIM * NDIM + start;
    const float* Wp  = W + (size_t)(p * D + n0) * K;
    const float* wb0 = Wp + (size_t)r0 * K;
    const float* wb1 = wb0 + (size_t)8 * K;
    const int wA = 2048 * wid;                    // wave's A byte offset in stage

    auto STAGE = [&](int t, int sbase) {
        int f = t * 32 + g4;
        if constexpr (TAIL) f = (f > FMAXC) ? FMAXC : f;   // garbage, zeroed at read
        int q = f >> WLOG2;
        int j = f & (WWIN - 1);
        const float* ga = xb0 + q * NDIM + j;
        char* la = ldsraw + sbase + wA;
        char* lb = ldsraw + sbase + 8192 + wA;
        gload16(ga, la);
        gload16(ga + (size_t)8 * QDIM * NDIM, la + 1024);
        gload16(wb0 + f, lb);
        gload16(wb1 + f, lb + 1024);
    };

    // ---- fragment-read constants (swizzled): (wm|wn)+16 keeps r&7 == lr&7
    const int x7 = lr & 7;
    const int c0 = ((hi * 2)     ^ x7) * 16;
    const int c1 = ((hi * 2 + 1) ^ x7) * 16;
    const int oA0 = (wm + lr) * 128;
    const int oA1 = (wm + 16 + lr) * 128;
    const int oB0 = 8192 + (wn + lr) * 128;
    const int oB1 = 8192 + (wn + 16 + lr) * 128;

    f32x4 acc[2][2] = {};

    STAGE(0, 0);
    STAGE(1, 16384);

    int cs = 0;   // byte base of current tile's stage
    #pragma unroll 1
    for (int t = 0; t < G; ++t) {
        if (t + 1 < G) { asm volatile("s_waitcnt vmcnt(4)" ::: "memory"); }
        else           { asm volatile("s_waitcnt vmcnt(0)" ::: "memory"); }
        __builtin_amdgcn_sched_barrier(0);
        __builtin_amdgcn_s_barrier();
        __builtin_amdgcn_sched_barrier(0);

        const char* sb = ldsraw + cs;
        float4 a00 = *(const float4*)(sb + oA0 + c0);
        float4 a01 = *(const float4*)(sb + oA0 + c1);
        float4 a10 = *(const float4*)(sb + oA1 + c0);
        float4 a11 = *(const float4*)(sb + oA1 + c1);
        float4 b00 = *(const float4*)(sb + oB0 + c0);
        float4 b01 = *(const float4*)(sb + oB0 + c1);
        float4 b10 = *(const float4*)(sb + oB1 + c0);
        float4 b11 = *(const float4*)(sb + oB1 + c1);

        if constexpr (TAIL) {
            if (t == G - 1 && kb >= (K & 31)) {     // fully-invalid fragments
                float4 z = make_float4(0.f, 0.f, 0.f, 0.f);
                a00 = z; a01 = z; a10 = z; a11 = z;
            }
        }

        bf16x8s A0 = pack8(a00, a01);
        bf16x8s A1 = pack8(a10, a11);
        bf16x8s B0 = pack8(b00, b01);
        bf16x8s B1 = pack8(b10, b11);

        acc[0][0] = __builtin_amdgcn_mfma_f32_16x16x32_bf16(A0, B0, acc[0][0], 0, 0, 0);
        acc[0][1] = __builtin_amdgcn_mfma_f32_16x16x32_bf16(A0, B1, acc[0][1], 0, 0, 0);
        acc[1][0] = __builtin_amdgcn_mfma_f32_16x16x32_bf16(A1, B0, acc[1][0], 0, 0, 0);
        acc[1][1] = __builtin_amdgcn_mfma_f32_16x16x32_bf16(A1, B1, acc[1][1], 0, 0, 0);

        __builtin_amdgcn_sched_barrier(0);
        if (t + 2 < G) {
            int pb = (cs == 0) ? 32768 : cs - 16384;   // stage (t+2)%3 == (t-1)%3
            STAGE(t + 2, pb);
        }
        cs = (cs == 32768) ? 0 : cs + 16384;
    }

    // epilogue: C/D layout col = lane&15, row = (lane>>4)*4 + r
    const int colbase = p * D + n0;
    #pragma unroll
    for (int mi = 0; mi < 2; ++mi) {
        #pragma unroll
        for (int ni = 0; ni < 2; ++ni) {
            int col = colbase + wn + ni * 16 + lr;
            int rbase = wm + mi * 16 + hi * 4;
            #pragma unroll
            for (int r = 0; r < 4; ++r) {
                out[(size_t)(rbase + r) * OUTSTRIDE + col] = acc[mi][ni][r];
            }
        }
    }
}

// Fused dispatch: 1000 blocks. PER-SEGMENT XCD chunk swizzle: balance (every
// XCD gets ~1/8 of each filterbank's blocks) + locality (contiguous p-range
// per XCD per filterbank -> x-slice ~1.2 MB, L2-resident).
__global__ __launch_bounds__(256, 3)
void fbk_fused(const float* __restrict__ x,  const float* __restrict__ w0,
               const float* __restrict__ w1, const float* __restrict__ w2,
               float* __restrict__ out) {
    __shared__ __align__(16) char ldsraw[49152];   // 3 stages x 16 KB -> 3 blocks/CU
    const int pb = blockIdx.x;
    if (pb < 328) {
        // fb2: w=64, s=16, d=256, P=82, K=1344, 4 n-tiles
        fbk_body<6, 4, 256, 82, 16, 1344>(x, w2, out + 43008, chunk_swz(pb, 328), ldsraw);
    } else if (pb < 662) {
        // fb1: w=32, s=8, d=128, P=167, K=672, 2 n-tiles
        fbk_body<5, 2, 128, 167, 8, 672>(x, w1, out + 21632, chunk_swz(pb - 328, 334), ldsraw);
    } else {
        // fb0: w=16, s=4, d=64, P=338, K=336, 1 n-tile
        fbk_body<4, 1, 64, 338, 4, 336>(x, w0, out, chunk_swz(pb - 662, 338), ldsraw);
    }
}

extern "C" void kernel_launch(void* const* d_in, const int* in_sizes, int n_in,
                              void* d_out, int out_size, void* d_ws, size_t ws_size,
                              hipStream_t stream) {
    const float* x  = (const float*)d_in[0];
    const float* w0 = (const float*)d_in[1];
    const float* w1 = (const float*)d_in[2];
    const float* w2 = (const float*)d_in[3];
    float* out = (float*)d_out;
    fbk_fused<<<dim3(1000), 256, 0, stream>>>(x, w0, w1, w2, out);
}